// Round 6
// baseline (256.248 us; speedup 1.0000x reference)
//
#include <hip/hip_runtime.h>
#include <hip/hip_bf16.h>

#define NB 32
#define NN 8400
#define NC 80
#define KPRE 512
#define MAXOUT 100
#define NGRP 66   // ceil(8400 / 128) blocks per image; 2 groups of 64 rows per block

// ---------------- Kernel A: scores + per-block max (float4 LDS staging) ----------------
__global__ __launch_bounds__(128) void score_kernel(const float* __restrict__ pred,
                                                    float* __restrict__ scores,
                                                    unsigned* __restrict__ wmaxg) {
    int b = blockIdx.y;
    int w = threadIdx.x >> 6, lane = threadIdx.x & 63;
    int g = blockIdx.x * 2 + w;                    // 64-row group in image
    __shared__ float4 stg4[2][1360];               // 64 rows x 85 floats = 1360 float4
    const float4* p4 = (const float4*)pred;
    size_t base4 = (size_t)b * 178500 + (size_t)g * 1360;   // (b*8400 + g*64)*85/4
    size_t img_end4 = ((size_t)b + 1) * 178500;
    for (int k = lane; k < 1360; k += 64) {
        size_t e = base4 + k;
        if (e >= img_end4) e = img_end4 - 1;       // clamp tail (pad rows discarded below)
        stg4[w][k] = p4[e];
    }
    __syncthreads();
    int row = g * 64 + lane;
    const float* r = (const float*)&stg4[w][0] + lane * 85;  // stride 85 dwords: conflict-free
    float obj = r[4];
    float cc = r[5];
    for (int c = 6; c < 85; c++) cc = fmaxf(cc, r[c]);
    float s = __fmul_rn(obj, cc);
    if (row < NN) scores[(size_t)b * NN + row] = s;
    else s = 0.0f;                                 // pad rows must not pollute the max
    unsigned bits = __float_as_uint(s);
    for (int o = 32; o > 0; o >>= 1) {
        unsigned other = (unsigned)__shfl_down((int)bits, o, 64);
        if (other > bits) bits = other;
    }
    __shared__ unsigned wmax[2];
    if (lane == 0) wmax[w] = bits;
    __syncthreads();
    if (threadIdx.x == 0) {
        unsigned m = wmax[0] > wmax[1] ? wmax[0] : wmax[1];
        wmaxg[b * NGRP + blockIdx.x] = m;          // every slot written -> no init needed
    }
}

// ---- wave-0 helper: largest bin B with suffix(B) >= T over hist[0..nb); R = T - suffix(B+1)
__device__ __forceinline__ void find_bin(const unsigned* hist, int nb, unsigned T, int lane,
                                         int* outB, unsigned* outR) {
    unsigned running = 0;
    for (int c = nb / 64 - 1; c >= 0; c--) {
        unsigned v = hist[c * 64 + lane];
        unsigned s = v;
        for (int off = 1; off < 64; off <<= 1) {
            unsigned u = (unsigned)__shfl_down((int)s, off, 64);
            if (lane + off < 64) s += u;
        }
        unsigned total0 = (unsigned)__shfl((int)s, 0, 64);
        if (total0 + running >= T) {
            unsigned long long mask = __ballot(s + running >= T);
            int m = 63 - __clzll(mask);
            unsigned sm = (unsigned)__shfl((int)s, m, 64);
            unsigned vm = (unsigned)__shfl((int)v, m, 64);
            if (lane == 0) { *outB = c * 64 + m; *outR = T - (sm + running - vm); }
            return;
        }
        running += total0;
    }
    if (lane == 0) { *outB = 0; *outR = T; }
}

// ---------------- Kernel B: top-512 radix select + decode (fused) ----------------
__global__ __launch_bounds__(256) void select_kernel(const float* __restrict__ scores,
                                                     const unsigned* __restrict__ wmaxg,
                                                     const float* __restrict__ pred,
                                                     int* __restrict__ nvalid,
                                                     float4* __restrict__ boxoff,
                                                     float4* __restrict__ boxraw,
                                                     float4* __restrict__ meta) {
    int b = blockIdx.x, t = threadIdx.x;
    __shared__ unsigned skey[NN];                 // 33.6 KB
    __shared__ unsigned hist[2048];               // 8 KB
    __shared__ unsigned long long list[KPRE];     // 4 KB
    __shared__ unsigned long long sorted[KPRE];   // 4 KB
    __shared__ int elist[256];
    __shared__ int S_B[3];
    __shared__ unsigned S_T[3];
    __shared__ int S_cnt, S_ecnt;
    __shared__ float S_conf;

    if (t == 0) { S_cnt = 0; S_ecnt = 0; }
    // reduce per-block maxima -> conf
    if (t < 64) {
        unsigned m = wmaxg[b * NGRP + t];
        if (t + 64 < NGRP) { unsigned m2 = wmaxg[b * NGRP + t + 64]; if (m2 > m) m = m2; }
        for (int off = 32; off > 0; off >>= 1) {
            unsigned o = (unsigned)__shfl_down((int)m, off, 64);
            if (o > m) m = o;
        }
        if (t == 0) S_conf = fminf(0.25f, __uint_as_float(m));
    }
    for (int i = t; i < 2048; i += 256) hist[i] = 0;
    __syncthreads();
    float conf = S_conf;
    const float4* sc4 = (const float4*)(scores + (size_t)b * NN);
    for (int n = t; n < NN / 4; n += 256) {
        float4 v = sc4[n];
        skey[n * 4 + 0] = (v.x >= conf) ? __float_as_uint(v.x) : 0u;
        skey[n * 4 + 1] = (v.y >= conf) ? __float_as_uint(v.y) : 0u;
        skey[n * 4 + 2] = (v.z >= conf) ? __float_as_uint(v.z) : 0u;
        skey[n * 4 + 3] = (v.w >= conf) ? __float_as_uint(v.w) : 0u;
    }
    __syncthreads();
    // pass A: bits[31:21]
    for (int n = t; n < NN; n += 256) atomicAdd(&hist[skey[n] >> 21], 1u);
    __syncthreads();
    if (t < 64) find_bin(hist, 2048, 512u, t, &S_B[0], &S_T[0]);
    __syncthreads();
    int B1 = S_B[0]; unsigned R1 = S_T[0];
    for (int i = t; i < 2048; i += 256) hist[i] = 0;
    __syncthreads();
    // pass B: bits[20:10] within top11==B1
    for (int n = t; n < NN; n += 256) {
        unsigned k = skey[n];
        if ((int)(k >> 21) == B1) atomicAdd(&hist[(k >> 10) & 0x7FFu], 1u);
    }
    __syncthreads();
    if (t < 64) find_bin(hist, 2048, R1, t, &S_B[1], &S_T[1]);
    __syncthreads();
    unsigned P = ((unsigned)B1 << 11) | (unsigned)S_B[1];
    unsigned R2 = S_T[1];
    for (int i = t; i < 1024; i += 256) hist[i] = 0;
    __syncthreads();
    // pass C: bits[9:0] within top22==P
    for (int n = t; n < NN; n += 256) {
        unsigned k = skey[n];
        if ((k >> 10) == P) atomicAdd(&hist[k & 0x3FFu], 1u);
    }
    __syncthreads();
    if (t < 64) find_bin(hist, 1024, R2, t, &S_B[2], &S_T[2]);
    __syncthreads();
    unsigned K32 = (P << 10) | (unsigned)S_B[2];
    unsigned R3 = S_T[2];
    // compact winners (unordered) + boundary ties
    for (int n = t; n < NN; n += 256) {
        unsigned k = skey[n];
        if (k > K32) {
            int pos = atomicAdd(&S_cnt, 1);
            list[pos] = ((unsigned long long)k << 32) | (unsigned long long)(unsigned)(~(unsigned)n);
        }
        if (K32 != 0u && k == K32) {
            int ep = atomicAdd(&S_ecnt, 1);
            if (ep < 256) elist[ep] = n;
        }
    }
    __syncthreads();
    int ecnt = S_ecnt; if (ecnt > 256) ecnt = 256;
    if (t < ecnt) {
        int my = elist[t];
        int r = 0;
        for (int j = 0; j < ecnt; j++) r += (elist[j] < my) ? 1 : 0;
        if ((unsigned)r < R3) {
            int pos = atomicAdd(&S_cnt, 1);
            list[pos] = ((unsigned long long)K32 << 32) | (unsigned long long)(unsigned)(~(unsigned)my);
        }
    }
    __syncthreads();
    int cnt = S_cnt;
    if (t == 0) nvalid[b] = cnt;
    for (int i = cnt + t; i < KPRE; i += 256) list[i] = 0ull;
    __syncthreads();
    // exact rank via all-pairs compare -> sorted order in LDS
    unsigned long long K0 = list[t], K1 = list[t + 256];
    int r0 = 0, r1 = 0;
    for (int j = 0; j < KPRE; j++) {
        unsigned long long L = list[j];
        r0 += (L > K0) ? 1 : 0;
        r1 += (L > K1) ? 1 : 0;
    }
    if (K0 != 0ull) sorted[r0] = K0; else sorted[t] = 0ull;
    if (K1 != 0ull) sorted[r1] = K1; else sorted[t + 256] = 0ull;
    __syncthreads();
    // fused decode: gather pred rows for the sorted top-512, write SoA
    for (int rr = t; rr < KPRE; rr += 256) {
        unsigned long long key = sorted[rr];
        int valid = ((unsigned)(key >> 32)) != 0u;
        unsigned n = ~(unsigned)key;
        if (!valid) n = 0;
        const float* p = pred + ((size_t)b * NN + n) * 85;
        float cx = p[0], cy = p[1], w = p[2], h = p[3], obj = p[4];
        float cc = p[5];
        int cp = 0;
        for (int c = 1; c < NC; c++) {
            float v = p[5 + c];
            if (v > cc) { cc = v; cp = c; }
        }
        float hw = __fmul_rn(w, 0.5f), hh = __fmul_rn(h, 0.5f);
        float x1 = cx - hw, y1 = cy - hh, x2 = cx + hw, y2 = cy + hh;
        float off = __fmul_rn((float)cp, 4096.0f);
        size_t o = (size_t)(b << 9) + rr;
        boxraw[o] = make_float4(x1, y1, x2, y2);
        boxoff[o] = make_float4(x1 + off, y1 + off, x2 + off, y2 + off);
        meta[o] = make_float4(obj, cc, (float)cp, valid ? 1.0f : 0.0f);
    }
}

// ---------------- Kernel C: IoU bitmatrix build (massively parallel) ----------------
__global__ __launch_bounds__(256) void iou_kernel(const float4* __restrict__ boxoff,
                                                  unsigned long long* __restrict__ ioug) {
    int b = blockIdx.y, t = threadIdx.x;
    int r = blockIdx.x * 64 + (t >> 2);
    int q = t & 3;
    __shared__ float4 sb[KPRE];
    for (int i = t; i < KPRE; i += 256) sb[i] = boxoff[(size_t)(b << 9) + i];
    __syncthreads();
    float4 bi = sb[r];
    float ai = __fmul_rn(bi.z - bi.x, bi.w - bi.y);
    unsigned long long w0 = 0ull, w1 = 0ull;
    int base = q * 128, rot = q * 33;
    for (int s = 0; s < 128; s++) {
        int jj = (s + rot) & 127;
        int jc = base + jj;
        float4 bj = sb[jc];
        float xx1 = fmaxf(bi.x, bj.x);
        float yy1 = fmaxf(bi.y, bj.y);
        float xx2 = fminf(bi.z, bj.z);
        float yy2 = fminf(bi.w, bj.w);
        float iw = fmaxf(xx2 - xx1, 0.0f);
        float ih = fmaxf(yy2 - yy1, 0.0f);
        float inter = __fmul_rn(iw, ih);
        float aj = __fmul_rn(bj.z - bj.x, bj.w - bj.y);
        float uni = (ai + aj) - inter;
        float iou = inter / (uni + 1e-9f);
        if (iou > 0.45f && jc < r) {
            if (jj < 64) w0 |= 1ull << jj;
            else         w1 |= 1ull << (jj - 64);
        }
    }
    size_t rowbase = ((size_t)(b << 9) + r) * 8 + q * 2;
    ioug[rowbase]     = w0;
    ioug[rowbase + 1] = w1;
}

// ---------------- Kernel D: sequential greedy scan + output ----------------
__global__ __launch_bounds__(64) void scan_kernel(const unsigned long long* __restrict__ ioug,
                                                  const int* __restrict__ nvalid,
                                                  const float4* __restrict__ boxraw,
                                                  const float4* __restrict__ meta,
                                                  float* __restrict__ out) {
    int b = blockIdx.x, t = threadIdx.x;
    __shared__ unsigned long long sl[528 * 8];      // 512 rows + 16 pad rows
    __shared__ unsigned long long skeep[8];

    const ulonglong2* src = (const ulonglong2*)(ioug + ((size_t)b << 12));
    ulonglong2* dst = (ulonglong2*)sl;
    for (int it = 0; it < 32; it++) dst[it * 64 + t] = src[it * 64 + t];
    sl[4096 + t] = 0ull;
    sl[4160 + t] = 0ull;
    __syncthreads();

    int w8 = t & 7;
    int nval = nvalid[b];
    unsigned long long keepW = 0ull;

#define STEP(ii, rwreg) { \
        bool hit = ((rwreg) & keepW) != 0ull; \
        unsigned long long bal = __ballot(hit); \
        bool kept = (bal == 0ull) && ((ii) < nval); \
        unsigned long long sb_ = (kept && (t == ((ii) >> 6))) ? (1ull << ((ii) & 63)) : 0ull; \
        keepW |= sb_; }

    unsigned long long A[8], Bf[8];
#pragma unroll
    for (int k = 0; k < 8; k++) A[k] = sl[(size_t)(0 + k) * 8 + w8];
#pragma unroll
    for (int k = 0; k < 8; k++) Bf[k] = sl[(size_t)(8 + k) * 8 + w8];
    for (int g = 0; g < 64; g += 2) {
        int base = g * 8;
#pragma unroll
        for (int k = 0; k < 8; k++) { STEP(base + k, A[k]); }
#pragma unroll
        for (int k = 0; k < 8; k++) A[k] = sl[(size_t)(base + 16 + k) * 8 + w8];
#pragma unroll
        for (int k = 0; k < 8; k++) { STEP(base + 8 + k, Bf[k]); }
#pragma unroll
        for (int k = 0; k < 8; k++) Bf[k] = sl[(size_t)(base + 24 + k) * 8 + w8];
    }
#undef STEP

    if (t < 8) skeep[t] = keepW;
    __syncthreads();

    float* dets = out + (size_t)b * (MAXOUT * 7);
    float* mask = out + (size_t)NB * MAXOUT * 7 + (size_t)b * MAXOUT;
    for (int m = t; m < MAXOUT * 7; m += 64) dets[m] = 0.0f;
    for (int m = t; m < MAXOUT; m += 64) mask[m] = 0.0f;

    for (int c = t; c < KPRE; c += 64) {
        int wq = c >> 6;
        unsigned long long kw = skeep[wq];
        int kept_c = (int)((kw >> (c & 63)) & 1ull);
        if (!kept_c) continue;
        int rank = 0;
        for (int w2 = 0; w2 < wq; w2++) rank += __popcll(skeep[w2]);
        rank += __popcll(kw & ((1ull << (c & 63)) - 1ull));
        if (rank < MAXOUT) {
            float4 rb = boxraw[(size_t)(b << 9) + c];
            float4 mt = meta[(size_t)(b << 9) + c];
            float* row = dets + rank * 7;
            row[0] = rb.x; row[1] = rb.y; row[2] = rb.z; row[3] = rb.w;
            row[4] = mt.x; row[5] = mt.y; row[6] = mt.z;
            mask[rank] = 1.0f;
        }
    }
}

extern "C" void kernel_launch(void* const* d_in, const int* in_sizes, int n_in,
                              void* d_out, int out_size, void* d_ws, size_t ws_size,
                              hipStream_t stream) {
    const float* pred = (const float*)d_in[0];
    float* out = (float*)d_out;

    char* ws = (char*)d_ws;
    unsigned* wmaxg = (unsigned*)ws;                                   // 32*66*4 = 8448 -> pad 8704
    float* scores = (float*)(ws + 8704);                               // 1,075,200 -> 1,083,904
    int* nvalid = (int*)(ws + 1083904);                                // 128      -> 1,084,032
    float4* boxoff = (float4*)(ws + 1084032);                          // 262,144  -> 1,346,176
    float4* boxraw = (float4*)(ws + 1346176);                          // 262,144  -> 1,608,320
    float4* meta   = (float4*)(ws + 1608320);                          // 262,144  -> 1,870,464
    unsigned long long* ioug = (unsigned long long*)(ws + 1870464);    // 1,048,576 (16B-aligned)

    dim3 gA(NGRP, NB);
    score_kernel<<<gA, 128, 0, stream>>>(pred, scores, wmaxg);
    select_kernel<<<NB, 256, 0, stream>>>(scores, wmaxg, pred, nvalid, boxoff, boxraw, meta);
    dim3 gI(8, NB);
    iou_kernel<<<gI, 256, 0, stream>>>(boxoff, ioug);
    scan_kernel<<<NB, 64, 0, stream>>>(ioug, nvalid, boxraw, meta, out);
}

// Round 7
// 234.070 us; speedup vs baseline: 1.0947x; 1.0947x over previous
//
#include <hip/hip_runtime.h>
#include <hip/hip_bf16.h>

#define NB 32
#define NN 8400
#define NC 80
#define KPRE 512
#define MAXOUT 100
#define NGRP 66   // ceil(8400 / 128) blocks per image; 2 groups of 64 rows per block

// ---------------- Kernel A: scores + per-anchor decode + per-block max ----------------
// Streams all of pred once (coalesced float4 staging). Computes score, argmax class,
// raw box; writes scores (4B), rawbox (16B), minfo (16B) per anchor — all coalesced.
__global__ __launch_bounds__(128) void score_kernel(const float* __restrict__ pred,
                                                    float* __restrict__ scores,
                                                    unsigned* __restrict__ wmaxg,
                                                    float4* __restrict__ rawbox,
                                                    float4* __restrict__ minfo) {
    int b = blockIdx.y;
    int w = threadIdx.x >> 6, lane = threadIdx.x & 63;
    int g = blockIdx.x * 2 + w;                    // 64-row group in image
    __shared__ float4 stg4[2][1360];               // 64 rows x 85 floats
    const float4* p4 = (const float4*)pred;
    size_t base4 = (size_t)b * 178500 + (size_t)g * 1360;
    size_t img_end4 = ((size_t)b + 1) * 178500;
    for (int k = lane; k < 1360; k += 64) {
        size_t e = base4 + k;
        if (e >= img_end4) e = img_end4 - 1;       // clamp tail
        stg4[w][k] = p4[e];
    }
    __syncthreads();
    int row = g * 64 + lane;
    const float* r = (const float*)&stg4[w][0] + lane * 85;  // stride 85: 2-way bank alias (free)
    float cx = r[0], cy = r[1], bw = r[2], bh = r[3], obj = r[4];
    float cc = r[5];
    int cp = 0;
    for (int c = 1; c < NC; c++) {
        float v = r[5 + c];
        if (v > cc) { cc = v; cp = c; }            // strict > : first-max, matches argmax
    }
    float s = __fmul_rn(obj, cc);
    if (row < NN) {
        size_t idx = (size_t)b * NN + row;
        scores[idx] = s;
        float hw = __fmul_rn(bw, 0.5f), hh = __fmul_rn(bh, 0.5f);
        float x1 = cx - hw, y1 = cy - hh, x2 = cx + hw, y2 = cy + hh;
        rawbox[idx] = make_float4(x1, y1, x2, y2);
        minfo[idx]  = make_float4(obj, cc, (float)cp, s);
    } else {
        s = 0.0f;                                  // pad rows must not pollute the max
    }
    unsigned bits = __float_as_uint(s);
    for (int o = 32; o > 0; o >>= 1) {
        unsigned other = (unsigned)__shfl_down((int)bits, o, 64);
        if (other > bits) bits = other;
    }
    __shared__ unsigned wmax[2];
    if (lane == 0) wmax[w] = bits;
    __syncthreads();
    if (threadIdx.x == 0) {
        unsigned m = wmax[0] > wmax[1] ? wmax[0] : wmax[1];
        wmaxg[b * NGRP + blockIdx.x] = m;          // every slot written -> no init needed
    }
}

// ---- wave-0 helper: largest bin B with suffix(B) >= T over hist[0..nb); R = T - suffix(B+1)
__device__ __forceinline__ void find_bin(const unsigned* hist, int nb, unsigned T, int lane,
                                         int* outB, unsigned* outR) {
    unsigned running = 0;
    for (int c = nb / 64 - 1; c >= 0; c--) {
        unsigned v = hist[c * 64 + lane];
        unsigned s = v;
        for (int off = 1; off < 64; off <<= 1) {
            unsigned u = (unsigned)__shfl_down((int)s, off, 64);
            if (lane + off < 64) s += u;
        }
        unsigned total0 = (unsigned)__shfl((int)s, 0, 64);
        if (total0 + running >= T) {
            unsigned long long mask = __ballot(s + running >= T);
            int m = 63 - __clzll(mask);
            unsigned sm = (unsigned)__shfl((int)s, m, 64);
            unsigned vm = (unsigned)__shfl((int)v, m, 64);
            if (lane == 0) { *outB = c * 64 + m; *outR = T - (sm + running - vm); }
            return;
        }
        running += total0;
    }
    if (lane == 0) { *outB = 0; *outR = T; }
}

// ---------------- Kernel B: top-512 radix select + tiny gather (1024 threads) ----------------
__global__ __launch_bounds__(1024) void select_kernel(const float* __restrict__ scores,
                                                      const unsigned* __restrict__ wmaxg,
                                                      const float4* __restrict__ rawbox,
                                                      const float4* __restrict__ minfo,
                                                      int* __restrict__ nvalid,
                                                      float4* __restrict__ boxoff,
                                                      float4* __restrict__ boxraw,
                                                      float4* __restrict__ meta) {
    int b = blockIdx.x, t = threadIdx.x;
    __shared__ unsigned skey[NN];                 // 33.6 KB
    __shared__ unsigned hist[2048];               // 8 KB
    __shared__ unsigned long long list[KPRE];     // 4 KB
    __shared__ unsigned long long sorted[KPRE];   // 4 KB
    __shared__ int elist[256];
    __shared__ int S_B[3];
    __shared__ unsigned S_T[3];
    __shared__ int S_cnt, S_ecnt;
    __shared__ float S_conf;

    if (t == 0) { S_cnt = 0; S_ecnt = 0; }
    // reduce per-block maxima -> conf
    if (t < 64) {
        unsigned m = wmaxg[b * NGRP + t];
        if (t + 64 < NGRP) { unsigned m2 = wmaxg[b * NGRP + t + 64]; if (m2 > m) m = m2; }
        for (int off = 32; off > 0; off >>= 1) {
            unsigned o = (unsigned)__shfl_down((int)m, off, 64);
            if (o > m) m = o;
        }
        if (t == 0) S_conf = fminf(0.25f, __uint_as_float(m));
    }
    for (int i = t; i < 2048; i += 1024) hist[i] = 0;
    __syncthreads();
    float conf = S_conf;
    const float4* sc4 = (const float4*)(scores + (size_t)b * NN);
    for (int n = t; n < NN / 4; n += 1024) {
        float4 v = sc4[n];
        skey[n * 4 + 0] = (v.x >= conf) ? __float_as_uint(v.x) : 0u;
        skey[n * 4 + 1] = (v.y >= conf) ? __float_as_uint(v.y) : 0u;
        skey[n * 4 + 2] = (v.z >= conf) ? __float_as_uint(v.z) : 0u;
        skey[n * 4 + 3] = (v.w >= conf) ? __float_as_uint(v.w) : 0u;
    }
    __syncthreads();
    // pass A: bits[31:21]
    for (int n = t; n < NN; n += 1024) atomicAdd(&hist[skey[n] >> 21], 1u);
    __syncthreads();
    if (t < 64) find_bin(hist, 2048, 512u, t, &S_B[0], &S_T[0]);
    __syncthreads();
    int B1 = S_B[0]; unsigned R1 = S_T[0];
    for (int i = t; i < 2048; i += 1024) hist[i] = 0;
    __syncthreads();
    // pass B: bits[20:10] within top11==B1
    for (int n = t; n < NN; n += 1024) {
        unsigned k = skey[n];
        if ((int)(k >> 21) == B1) atomicAdd(&hist[(k >> 10) & 0x7FFu], 1u);
    }
    __syncthreads();
    if (t < 64) find_bin(hist, 2048, R1, t, &S_B[1], &S_T[1]);
    __syncthreads();
    unsigned P = ((unsigned)B1 << 11) | (unsigned)S_B[1];
    unsigned R2 = S_T[1];
    for (int i = t; i < 1024; i += 1024) hist[i] = 0;
    __syncthreads();
    // pass C: bits[9:0] within top22==P
    for (int n = t; n < NN; n += 1024) {
        unsigned k = skey[n];
        if ((k >> 10) == P) atomicAdd(&hist[k & 0x3FFu], 1u);
    }
    __syncthreads();
    if (t < 64) find_bin(hist, 1024, R2, t, &S_B[2], &S_T[2]);
    __syncthreads();
    unsigned K32 = (P << 10) | (unsigned)S_B[2];
    unsigned R3 = S_T[2];
    // compact winners (unordered) + boundary ties
    for (int n = t; n < NN; n += 1024) {
        unsigned k = skey[n];
        if (k > K32) {
            int pos = atomicAdd(&S_cnt, 1);
            list[pos] = ((unsigned long long)k << 32) | (unsigned long long)(unsigned)(~(unsigned)n);
        }
        if (K32 != 0u && k == K32) {
            int ep = atomicAdd(&S_ecnt, 1);
            if (ep < 256) elist[ep] = n;
        }
    }
    __syncthreads();
    int ecnt = S_ecnt; if (ecnt > 256) ecnt = 256;
    if (t < ecnt) {
        int my = elist[t];
        int r = 0;
        for (int j = 0; j < ecnt; j++) r += (elist[j] < my) ? 1 : 0;
        if ((unsigned)r < R3) {
            int pos = atomicAdd(&S_cnt, 1);
            list[pos] = ((unsigned long long)K32 << 32) | (unsigned long long)(unsigned)(~(unsigned)my);
        }
    }
    __syncthreads();
    int cnt = S_cnt;
    if (t == 0) nvalid[b] = cnt;
    for (int i = cnt + t; i < KPRE; i += 1024) list[i] = 0ull;
    __syncthreads();
    // exact rank via all-pairs compare -> sorted order in LDS
    if (t < KPRE) {
        unsigned long long K0 = list[t];
        int r0 = 0;
        for (int j = 0; j < KPRE; j++) {
            unsigned long long L = list[j];     // wave-uniform broadcast read
            r0 += (L > K0) ? 1 : 0;
        }
        if (K0 != 0ull) sorted[r0] = K0; else sorted[t] = 0ull;
    }
    __syncthreads();
    // tiny gather: two float4 loads per row (decode already done in score_kernel)
    if (t < KPRE) {
        unsigned long long key = sorted[t];
        int valid = ((unsigned)(key >> 32)) != 0u;
        unsigned n = ~(unsigned)key;
        if (!valid) n = 0;
        size_t src = (size_t)b * NN + n;
        float4 rb = rawbox[src];
        float4 mi = minfo[src];
        float off = __fmul_rn(mi.z, 4096.0f);
        size_t o = (size_t)(b << 9) + t;
        boxraw[o] = rb;
        boxoff[o] = make_float4(rb.x + off, rb.y + off, rb.z + off, rb.w + off);
        meta[o] = make_float4(mi.x, mi.y, mi.z, valid ? 1.0f : 0.0f);
    }
}

// ---------------- Kernel C: IoU bitmatrix build (massively parallel) ----------------
__global__ __launch_bounds__(256) void iou_kernel(const float4* __restrict__ boxoff,
                                                  unsigned long long* __restrict__ ioug) {
    int b = blockIdx.y, t = threadIdx.x;
    int r = blockIdx.x * 64 + (t >> 2);
    int q = t & 3;
    __shared__ float4 sb[KPRE];
    for (int i = t; i < KPRE; i += 256) sb[i] = boxoff[(size_t)(b << 9) + i];
    __syncthreads();
    float4 bi = sb[r];
    float ai = __fmul_rn(bi.z - bi.x, bi.w - bi.y);
    unsigned long long w0 = 0ull, w1 = 0ull;
    int base = q * 128, rot = q * 33;
    for (int s = 0; s < 128; s++) {
        int jj = (s + rot) & 127;
        int jc = base + jj;
        float4 bj = sb[jc];
        float xx1 = fmaxf(bi.x, bj.x);
        float yy1 = fmaxf(bi.y, bj.y);
        float xx2 = fminf(bi.z, bj.z);
        float yy2 = fminf(bi.w, bj.w);
        float iw = fmaxf(xx2 - xx1, 0.0f);
        float ih = fmaxf(yy2 - yy1, 0.0f);
        float inter = __fmul_rn(iw, ih);
        float aj = __fmul_rn(bj.z - bj.x, bj.w - bj.y);
        float uni = (ai + aj) - inter;
        float iou = inter / (uni + 1e-9f);
        if (iou > 0.45f && jc < r) {
            if (jj < 64) w0 |= 1ull << jj;
            else         w1 |= 1ull << (jj - 64);
        }
    }
    size_t rowbase = ((size_t)(b << 9) + r) * 8 + q * 2;
    ioug[rowbase]     = w0;
    ioug[rowbase + 1] = w1;
}

// ---------------- Kernel D: sequential greedy scan + output ----------------
__global__ __launch_bounds__(64) void scan_kernel(const unsigned long long* __restrict__ ioug,
                                                  const int* __restrict__ nvalid,
                                                  const float4* __restrict__ boxraw,
                                                  const float4* __restrict__ meta,
                                                  float* __restrict__ out) {
    int b = blockIdx.x, t = threadIdx.x;
    __shared__ unsigned long long sl[528 * 8];      // 512 rows + 16 pad rows
    __shared__ unsigned long long skeep[8];

    const ulonglong2* src = (const ulonglong2*)(ioug + ((size_t)b << 12));
    ulonglong2* dst = (ulonglong2*)sl;
    for (int it = 0; it < 32; it++) dst[it * 64 + t] = src[it * 64 + t];
    sl[4096 + t] = 0ull;
    sl[4160 + t] = 0ull;
    __syncthreads();

    int w8 = t & 7;
    int nval = nvalid[b];
    unsigned long long keepW = 0ull;

#define STEP(ii, rwreg) { \
        bool hit = ((rwreg) & keepW) != 0ull; \
        unsigned long long bal = __ballot(hit); \
        bool kept = (bal == 0ull) && ((ii) < nval); \
        unsigned long long sb_ = (kept && (t == ((ii) >> 6))) ? (1ull << ((ii) & 63)) : 0ull; \
        keepW |= sb_; }

    unsigned long long A[8], Bf[8];
#pragma unroll
    for (int k = 0; k < 8; k++) A[k] = sl[(size_t)(0 + k) * 8 + w8];
#pragma unroll
    for (int k = 0; k < 8; k++) Bf[k] = sl[(size_t)(8 + k) * 8 + w8];
    for (int g = 0; g < 64; g += 2) {
        int base = g * 8;
#pragma unroll
        for (int k = 0; k < 8; k++) { STEP(base + k, A[k]); }
#pragma unroll
        for (int k = 0; k < 8; k++) A[k] = sl[(size_t)(base + 16 + k) * 8 + w8];
#pragma unroll
        for (int k = 0; k < 8; k++) { STEP(base + 8 + k, Bf[k]); }
#pragma unroll
        for (int k = 0; k < 8; k++) Bf[k] = sl[(size_t)(base + 24 + k) * 8 + w8];
    }
#undef STEP

    if (t < 8) skeep[t] = keepW;
    __syncthreads();

    float* dets = out + (size_t)b * (MAXOUT * 7);
    float* mask = out + (size_t)NB * MAXOUT * 7 + (size_t)b * MAXOUT;
    for (int m = t; m < MAXOUT * 7; m += 64) dets[m] = 0.0f;
    for (int m = t; m < MAXOUT; m += 64) mask[m] = 0.0f;

    for (int c = t; c < KPRE; c += 64) {
        int wq = c >> 6;
        unsigned long long kw = skeep[wq];
        int kept_c = (int)((kw >> (c & 63)) & 1ull);
        if (!kept_c) continue;
        int rank = 0;
        for (int w2 = 0; w2 < wq; w2++) rank += __popcll(skeep[w2]);
        rank += __popcll(kw & ((1ull << (c & 63)) - 1ull));
        if (rank < MAXOUT) {
            float4 rb = boxraw[(size_t)(b << 9) + c];
            float4 mt = meta[(size_t)(b << 9) + c];
            float* row = dets + rank * 7;
            row[0] = rb.x; row[1] = rb.y; row[2] = rb.z; row[3] = rb.w;
            row[4] = mt.x; row[5] = mt.y; row[6] = mt.z;
            mask[rank] = 1.0f;
        }
    }
}

extern "C" void kernel_launch(void* const* d_in, const int* in_sizes, int n_in,
                              void* d_out, int out_size, void* d_ws, size_t ws_size,
                              hipStream_t stream) {
    const float* pred = (const float*)d_in[0];
    float* out = (float*)d_out;

    char* ws = (char*)d_ws;
    unsigned* wmaxg = (unsigned*)ws;                                   // 8448 -> pad 8704
    float* scores = (float*)(ws + 8704);                               // 1,075,200 -> 1,083,904
    int* nvalid = (int*)(ws + 1083904);                                // -> 1,084,032
    float4* boxoff = (float4*)(ws + 1084032);                          // -> 1,346,176
    float4* boxraw = (float4*)(ws + 1346176);                          // -> 1,608,320
    float4* meta   = (float4*)(ws + 1608320);                          // -> 1,870,464
    unsigned long long* ioug = (unsigned long long*)(ws + 1870464);    // -> 2,919,040
    float4* rawbox = (float4*)(ws + 2919040);                          // 32*8400*16 = 4,300,800 -> 7,219,840
    float4* minfo  = (float4*)(ws + 7219840);                          // 4,300,800 -> 11,520,640

    dim3 gA(NGRP, NB);
    score_kernel<<<gA, 128, 0, stream>>>(pred, scores, wmaxg, rawbox, minfo);
    select_kernel<<<NB, 1024, 0, stream>>>(scores, wmaxg, rawbox, minfo, nvalid, boxoff, boxraw, meta);
    dim3 gI(8, NB);
    iou_kernel<<<gI, 256, 0, stream>>>(boxoff, ioug);
    scan_kernel<<<NB, 64, 0, stream>>>(ioug, nvalid, boxraw, meta, out);
}

// Round 8
// 217.966 us; speedup vs baseline: 1.1756x; 1.0739x over previous
//
#include <hip/hip_runtime.h>
#include <hip/hip_bf16.h>

#define NB 32
#define NN 8400
#define NC 80
#define KPRE 512
#define MAXOUT 100
#define NGRP 132   // blocks per image; each block = 2 waves x 32 rows = 64 rows

// ---------------- Kernel A: scores + per-anchor decode + per-block max ----------------
// Each wave stages 32 rows (680 float4 = 10.9 KB) -> block LDS 21.8 KB -> 7 blocks/CU.
// Lane pair (2r, 2r+1) shares row r: h=lane&1 scans classes 40h..40h+39; shfl_xor combine.
__global__ __launch_bounds__(128) void score_kernel(const float* __restrict__ pred,
                                                    float* __restrict__ scores,
                                                    unsigned* __restrict__ wmaxg,
                                                    float4* __restrict__ rawbox,
                                                    float4* __restrict__ minfo) {
    int b = blockIdx.y;
    int w = threadIdx.x >> 6, lane = threadIdx.x & 63;
    int g = blockIdx.x * 2 + w;                    // 32-row group in image
    __shared__ float4 stg4[2][680];                // 32 rows x 85 floats per wave
    const float4* p4 = (const float4*)pred;
    size_t base4 = (size_t)b * 178500 + (size_t)g * 680;
    size_t img_end4 = ((size_t)b + 1) * 178500;
    for (int k = lane; k < 680; k += 64) {
        size_t e = base4 + k;
        if (e >= img_end4) e = img_end4 - 1;       // clamp tail (pad rows discarded below)
        stg4[w][k] = p4[e];
    }
    __syncthreads();
    int rl = lane >> 1, h = lane & 1;
    int row = g * 32 + rl;
    const float* r = (const float*)&stg4[w][0] + rl * 85;
    float cx = r[0], cy = r[1], bw = r[2], bh = r[3], obj = r[4];
    // half-class scan: h=0 -> classes 0..39, h=1 -> 40..79
    int c0 = 5 + h * 40;
    float cc = r[c0];
    int cp = h * 40;
    for (int c = 1; c < 40; c++) {
        float v = r[c0 + c];
        if (v > cc) { cc = v; cp = h * 40 + c; }   // strict >: first-max within half
    }
    // combine pair: tie -> lower class index
    float cc1 = __shfl_xor(cc, 1, 64);
    int cp1 = __shfl_xor(cp, 1, 64);
    bool take = (cc1 > cc) || (cc1 == cc && cp1 < cp);
    cc = take ? cc1 : cc;
    cp = take ? cp1 : cp;
    float s = __fmul_rn(obj, cc);
    float hw = __fmul_rn(bw, 0.5f), hh = __fmul_rn(bh, 0.5f);
    float x1 = cx - hw, y1 = cy - hh, x2 = cx + hw, y2 = cy + hh;
    // redistribute: lane l<32 takes row l's result (lives in lane 2l), coalesced writes
    float v0 = __shfl(x1, (lane & 31) * 2, 64);
    float v1 = __shfl(y1, (lane & 31) * 2, 64);
    float v2 = __shfl(x2, (lane & 31) * 2, 64);
    float v3 = __shfl(y2, (lane & 31) * 2, 64);
    float v4 = __shfl(obj, (lane & 31) * 2, 64);
    float v5 = __shfl(cc, (lane & 31) * 2, 64);
    int   v6 = __shfl(cp, (lane & 31) * 2, 64);
    float v7 = __shfl(s, (lane & 31) * 2, 64);
    int wrow = g * 32 + (lane & 31);
    if (lane < 32 && wrow < NN) {
        size_t idx = (size_t)b * NN + wrow;
        scores[idx] = v7;
        rawbox[idx] = make_float4(v0, v1, v2, v3);
        minfo[idx]  = make_float4(v4, v5, (float)v6, v7);
    }
    // block max (pad rows -> 0)
    if (row >= NN) s = 0.0f;
    unsigned bits = __float_as_uint(s);
    for (int o = 32; o > 0; o >>= 1) {
        unsigned other = (unsigned)__shfl_down((int)bits, o, 64);
        if (other > bits) bits = other;
    }
    __shared__ unsigned wmax[2];
    if (lane == 0) wmax[w] = bits;
    __syncthreads();
    if (threadIdx.x == 0) {
        unsigned m = wmax[0] > wmax[1] ? wmax[0] : wmax[1];
        wmaxg[b * NGRP + blockIdx.x] = m;          // every slot written -> no init needed
    }
}

// ---- wave-0 helper: largest bin B with suffix(B) >= T over hist[0..nb); R = T - suffix(B+1)
__device__ __forceinline__ void find_bin(const unsigned* hist, int nb, unsigned T, int lane,
                                         int* outB, unsigned* outR) {
    unsigned running = 0;
    for (int c = nb / 64 - 1; c >= 0; c--) {
        unsigned v = hist[c * 64 + lane];
        unsigned s = v;
        for (int off = 1; off < 64; off <<= 1) {
            unsigned u = (unsigned)__shfl_down((int)s, off, 64);
            if (lane + off < 64) s += u;
        }
        unsigned total0 = (unsigned)__shfl((int)s, 0, 64);
        if (total0 + running >= T) {
            unsigned long long mask = __ballot(s + running >= T);
            int m = 63 - __clzll(mask);
            unsigned sm = (unsigned)__shfl((int)s, m, 64);
            unsigned vm = (unsigned)__shfl((int)v, m, 64);
            if (lane == 0) { *outB = c * 64 + m; *outR = T - (sm + running - vm); }
            return;
        }
        running += total0;
    }
    if (lane == 0) { *outB = 0; *outR = T; }
}

// ---------------- Kernel B: top-512 radix select + tiny gather (1024 threads) ----------------
__global__ __launch_bounds__(1024) void select_kernel(const float* __restrict__ scores,
                                                      const unsigned* __restrict__ wmaxg,
                                                      const float4* __restrict__ rawbox,
                                                      const float4* __restrict__ minfo,
                                                      int* __restrict__ nvalid,
                                                      float4* __restrict__ boxoff,
                                                      float4* __restrict__ boxraw,
                                                      float4* __restrict__ meta) {
    int b = blockIdx.x, t = threadIdx.x;
    __shared__ unsigned skey[NN];                 // 33.6 KB
    __shared__ unsigned hist[2048];               // 8 KB
    __shared__ unsigned long long list[KPRE];     // 4 KB
    __shared__ unsigned long long sorted[KPRE];   // 4 KB
    __shared__ int elist[256];
    __shared__ int S_B[3];
    __shared__ unsigned S_T[3];
    __shared__ int S_cnt, S_ecnt;
    __shared__ float S_conf;

    if (t == 0) { S_cnt = 0; S_ecnt = 0; }
    // reduce per-block maxima -> conf
    if (t < 64) {
        unsigned m = 0;
        for (int i = t; i < NGRP; i += 64) {
            unsigned v = wmaxg[b * NGRP + i];
            if (v > m) m = v;
        }
        for (int off = 32; off > 0; off >>= 1) {
            unsigned o = (unsigned)__shfl_down((int)m, off, 64);
            if (o > m) m = o;
        }
        if (t == 0) S_conf = fminf(0.25f, __uint_as_float(m));
    }
    for (int i = t; i < 2048; i += 1024) hist[i] = 0;
    __syncthreads();
    float conf = S_conf;
    const float4* sc4 = (const float4*)(scores + (size_t)b * NN);
    for (int n = t; n < NN / 4; n += 1024) {
        float4 v = sc4[n];
        skey[n * 4 + 0] = (v.x >= conf) ? __float_as_uint(v.x) : 0u;
        skey[n * 4 + 1] = (v.y >= conf) ? __float_as_uint(v.y) : 0u;
        skey[n * 4 + 2] = (v.z >= conf) ? __float_as_uint(v.z) : 0u;
        skey[n * 4 + 3] = (v.w >= conf) ? __float_as_uint(v.w) : 0u;
    }
    __syncthreads();
    // pass A: bits[31:21]
    for (int n = t; n < NN; n += 1024) atomicAdd(&hist[skey[n] >> 21], 1u);
    __syncthreads();
    if (t < 64) find_bin(hist, 2048, 512u, t, &S_B[0], &S_T[0]);
    __syncthreads();
    int B1 = S_B[0]; unsigned R1 = S_T[0];
    for (int i = t; i < 2048; i += 1024) hist[i] = 0;
    __syncthreads();
    // pass B: bits[20:10] within top11==B1
    for (int n = t; n < NN; n += 1024) {
        unsigned k = skey[n];
        if ((int)(k >> 21) == B1) atomicAdd(&hist[(k >> 10) & 0x7FFu], 1u);
    }
    __syncthreads();
    if (t < 64) find_bin(hist, 2048, R1, t, &S_B[1], &S_T[1]);
    __syncthreads();
    unsigned P = ((unsigned)B1 << 11) | (unsigned)S_B[1];
    unsigned R2 = S_T[1];
    for (int i = t; i < 1024; i += 1024) hist[i] = 0;
    __syncthreads();
    // pass C: bits[9:0] within top22==P
    for (int n = t; n < NN; n += 1024) {
        unsigned k = skey[n];
        if ((k >> 10) == P) atomicAdd(&hist[k & 0x3FFu], 1u);
    }
    __syncthreads();
    if (t < 64) find_bin(hist, 1024, R2, t, &S_B[2], &S_T[2]);
    __syncthreads();
    unsigned K32 = (P << 10) | (unsigned)S_B[2];
    unsigned R3 = S_T[2];
    // compact winners (unordered) + boundary ties
    for (int n = t; n < NN; n += 1024) {
        unsigned k = skey[n];
        if (k > K32) {
            int pos = atomicAdd(&S_cnt, 1);
            list[pos] = ((unsigned long long)k << 32) | (unsigned long long)(unsigned)(~(unsigned)n);
        }
        if (K32 != 0u && k == K32) {
            int ep = atomicAdd(&S_ecnt, 1);
            if (ep < 256) elist[ep] = n;
        }
    }
    __syncthreads();
    int ecnt = S_ecnt; if (ecnt > 256) ecnt = 256;
    if (t < ecnt) {
        int my = elist[t];
        int r = 0;
        for (int j = 0; j < ecnt; j++) r += (elist[j] < my) ? 1 : 0;
        if ((unsigned)r < R3) {
            int pos = atomicAdd(&S_cnt, 1);
            list[pos] = ((unsigned long long)K32 << 32) | (unsigned long long)(unsigned)(~(unsigned)my);
        }
    }
    __syncthreads();
    int cnt = S_cnt;
    if (t == 0) nvalid[b] = cnt;
    for (int i = cnt + t; i < KPRE; i += 1024) list[i] = 0ull;
    __syncthreads();
    // exact rank via all-pairs compare -> sorted order in LDS
    if (t < KPRE) {
        unsigned long long K0 = list[t];
        int r0 = 0;
        for (int j = 0; j < KPRE; j++) {
            unsigned long long L = list[j];     // wave-uniform broadcast read
            r0 += (L > K0) ? 1 : 0;
        }
        if (K0 != 0ull) sorted[r0] = K0; else sorted[t] = 0ull;
    }
    __syncthreads();
    // tiny gather: two float4 loads per row (decode already done in score_kernel)
    if (t < KPRE) {
        unsigned long long key = sorted[t];
        int valid = ((unsigned)(key >> 32)) != 0u;
        unsigned n = ~(unsigned)key;
        if (!valid) n = 0;
        size_t src = (size_t)b * NN + n;
        float4 rb = rawbox[src];
        float4 mi = minfo[src];
        float off = __fmul_rn(mi.z, 4096.0f);
        size_t o = (size_t)(b << 9) + t;
        boxraw[o] = rb;
        boxoff[o] = make_float4(rb.x + off, rb.y + off, rb.z + off, rb.w + off);
        meta[o] = make_float4(mi.x, mi.y, mi.z, valid ? 1.0f : 0.0f);
    }
}

// ---------------- Kernel C: IoU bitmatrix build (massively parallel) ----------------
__global__ __launch_bounds__(256) void iou_kernel(const float4* __restrict__ boxoff,
                                                  unsigned long long* __restrict__ ioug) {
    int b = blockIdx.y, t = threadIdx.x;
    int r = blockIdx.x * 64 + (t >> 2);
    int q = t & 3;
    __shared__ float4 sb[KPRE];
    for (int i = t; i < KPRE; i += 256) sb[i] = boxoff[(size_t)(b << 9) + i];
    __syncthreads();
    float4 bi = sb[r];
    float ai = __fmul_rn(bi.z - bi.x, bi.w - bi.y);
    unsigned long long w0 = 0ull, w1 = 0ull;
    int base = q * 128, rot = q * 33;
    for (int s = 0; s < 128; s++) {
        int jj = (s + rot) & 127;
        int jc = base + jj;
        float4 bj = sb[jc];
        float xx1 = fmaxf(bi.x, bj.x);
        float yy1 = fmaxf(bi.y, bj.y);
        float xx2 = fminf(bi.z, bj.z);
        float yy2 = fminf(bi.w, bj.w);
        float iw = fmaxf(xx2 - xx1, 0.0f);
        float ih = fmaxf(yy2 - yy1, 0.0f);
        float inter = __fmul_rn(iw, ih);
        float aj = __fmul_rn(bj.z - bj.x, bj.w - bj.y);
        float uni = (ai + aj) - inter;
        float iou = inter / (uni + 1e-9f);
        if (iou > 0.45f && jc < r) {
            if (jj < 64) w0 |= 1ull << jj;
            else         w1 |= 1ull << (jj - 64);
        }
    }
    size_t rowbase = ((size_t)(b << 9) + r) * 8 + q * 2;
    ioug[rowbase]     = w0;
    ioug[rowbase + 1] = w1;
}

// ---------------- Kernel D: sequential greedy scan + output ----------------
__global__ __launch_bounds__(64) void scan_kernel(const unsigned long long* __restrict__ ioug,
                                                  const int* __restrict__ nvalid,
                                                  const float4* __restrict__ boxraw,
                                                  const float4* __restrict__ meta,
                                                  float* __restrict__ out) {
    int b = blockIdx.x, t = threadIdx.x;
    __shared__ unsigned long long sl[528 * 8];      // 512 rows + 16 pad rows
    __shared__ unsigned long long skeep[8];

    const ulonglong2* src = (const ulonglong2*)(ioug + ((size_t)b << 12));
    ulonglong2* dst = (ulonglong2*)sl;
    for (int it = 0; it < 32; it++) dst[it * 64 + t] = src[it * 64 + t];
    sl[4096 + t] = 0ull;
    sl[4160 + t] = 0ull;
    __syncthreads();

    int w8 = t & 7;
    int nval = nvalid[b];
    unsigned long long keepW = 0ull;

#define STEP(ii, rwreg) { \
        bool hit = ((rwreg) & keepW) != 0ull; \
        unsigned long long bal = __ballot(hit); \
        bool kept = (bal == 0ull) && ((ii) < nval); \
        unsigned long long sb_ = (kept && (t == ((ii) >> 6))) ? (1ull << ((ii) & 63)) : 0ull; \
        keepW |= sb_; }

    unsigned long long A[8], Bf[8];
#pragma unroll
    for (int k = 0; k < 8; k++) A[k] = sl[(size_t)(0 + k) * 8 + w8];
#pragma unroll
    for (int k = 0; k < 8; k++) Bf[k] = sl[(size_t)(8 + k) * 8 + w8];
    for (int g = 0; g < 64; g += 2) {
        int base = g * 8;
#pragma unroll
        for (int k = 0; k < 8; k++) { STEP(base + k, A[k]); }
#pragma unroll
        for (int k = 0; k < 8; k++) A[k] = sl[(size_t)(base + 16 + k) * 8 + w8];
#pragma unroll
        for (int k = 0; k < 8; k++) { STEP(base + 8 + k, Bf[k]); }
#pragma unroll
        for (int k = 0; k < 8; k++) Bf[k] = sl[(size_t)(base + 24 + k) * 8 + w8];
    }
#undef STEP

    if (t < 8) skeep[t] = keepW;
    __syncthreads();

    float* dets = out + (size_t)b * (MAXOUT * 7);
    float* mask = out + (size_t)NB * MAXOUT * 7 + (size_t)b * MAXOUT;
    for (int m = t; m < MAXOUT * 7; m += 64) dets[m] = 0.0f;
    for (int m = t; m < MAXOUT; m += 64) mask[m] = 0.0f;

    for (int c = t; c < KPRE; c += 64) {
        int wq = c >> 6;
        unsigned long long kw = skeep[wq];
        int kept_c = (int)((kw >> (c & 63)) & 1ull);
        if (!kept_c) continue;
        int rank = 0;
        for (int w2 = 0; w2 < wq; w2++) rank += __popcll(skeep[w2]);
        rank += __popcll(kw & ((1ull << (c & 63)) - 1ull));
        if (rank < MAXOUT) {
            float4 rb = boxraw[(size_t)(b << 9) + c];
            float4 mt = meta[(size_t)(b << 9) + c];
            float* row = dets + rank * 7;
            row[0] = rb.x; row[1] = rb.y; row[2] = rb.z; row[3] = rb.w;
            row[4] = mt.x; row[5] = mt.y; row[6] = mt.z;
            mask[rank] = 1.0f;
        }
    }
}

extern "C" void kernel_launch(void* const* d_in, const int* in_sizes, int n_in,
                              void* d_out, int out_size, void* d_ws, size_t ws_size,
                              hipStream_t stream) {
    const float* pred = (const float*)d_in[0];
    float* out = (float*)d_out;

    char* ws = (char*)d_ws;
    unsigned* wmaxg = (unsigned*)ws;                                   // 32*132*4 = 16,896 -> pad 17,024
    float* scores = (float*)(ws + 17024);                              // 1,075,200 -> 1,092,224
    int* nvalid = (int*)(ws + 1092224);                                // 128 -> 1,092,352
    float4* boxoff = (float4*)(ws + 1092352);                          // 262,144 -> 1,354,496
    float4* boxraw = (float4*)(ws + 1354496);                          // 262,144 -> 1,616,640
    float4* meta   = (float4*)(ws + 1616640);                          // 262,144 -> 1,878,784
    unsigned long long* ioug = (unsigned long long*)(ws + 1878784);    // 1,048,576 -> 2,927,360
    float4* rawbox = (float4*)(ws + 2927360);                          // 4,300,800 -> 7,228,160
    float4* minfo  = (float4*)(ws + 7228160);                          // 4,300,800 -> 11,528,960

    dim3 gA(NGRP, NB);
    score_kernel<<<gA, 128, 0, stream>>>(pred, scores, wmaxg, rawbox, minfo);
    select_kernel<<<NB, 1024, 0, stream>>>(scores, wmaxg, rawbox, minfo, nvalid, boxoff, boxraw, meta);
    dim3 gI(8, NB);
    iou_kernel<<<gI, 256, 0, stream>>>(boxoff, ioug);
    scan_kernel<<<NB, 64, 0, stream>>>(ioug, nvalid, boxraw, meta, out);
}